// Round 2
// baseline (5706.961 us; speedup 1.0000x reference)
//
#include <hip/hip_runtime.h>
#include <math.h>

#define BATCH 16
#define CCH   512
#define HWS   4096                 // H*W
#define CHW   (CCH*HWS)            // per-batch elements: 2,097,152
#define DHFF  2048
#define NHEAD 8
#define HD    64
#define LNEPS 1e-5f

__device__ __forceinline__ float gelu_f(float x) {
    return 0.5f * x * (1.0f + erff(x * 0.70710678118654752440f));
}

// ---------- per-batch sum/sumsq (for LayerNorm), atomic partials ----------
__global__ __launch_bounds__(256) void stats_k(const float* __restrict__ src,
                                               float* __restrict__ st) {
    int b = blockIdx.y;
    const float4* p = (const float4*)(src + (size_t)b * CHW + (size_t)blockIdx.x * (CHW / 64));
    float s = 0.f, ss = 0.f;
    for (int i = threadIdx.x; i < (CHW / 64 / 4); i += 256) {
        float4 v = p[i];
        s  += v.x + v.y + v.z + v.w;
        ss += v.x * v.x + v.y * v.y + v.z * v.z + v.w * v.w;
    }
    __shared__ float r1[256], r2[256];
    int t = threadIdx.x;
    r1[t] = s; r2[t] = ss; __syncthreads();
    for (int o = 128; o > 0; o >>= 1) {
        if (t < o) { r1[t] += r1[t + o]; r2[t] += r2[t + o]; }
        __syncthreads();
    }
    if (t == 0) { atomicAdd(&st[2 * b], r1[0]); atomicAdd(&st[2 * b + 1], r2[0]); }
}

// ---------- residual add + stats (r = x + a), atomic partials; chunk-local ----------
__global__ __launch_bounds__(256) void resid_stats_k(const float* __restrict__ x,
                                                     const float* __restrict__ a,
                                                     float* __restrict__ r,
                                                     float* __restrict__ st) {
    int b = blockIdx.y;   // local within chunk
    size_t base = (size_t)b * CHW + (size_t)blockIdx.x * (CHW / 64);
    const float4* px = (const float4*)(x + base);
    const float4* pa = (const float4*)(a + base);
    float4* pr = (float4*)(r + base);
    float s = 0.f, ss = 0.f;
    for (int i = threadIdx.x; i < (CHW / 64 / 4); i += 256) {
        float4 vx = px[i], va = pa[i], v;
        v.x = vx.x + va.x; v.y = vx.y + va.y; v.z = vx.z + va.z; v.w = vx.w + va.w;
        pr[i] = v;
        s  += v.x + v.y + v.z + v.w;
        ss += v.x * v.x + v.y * v.y + v.z * v.z + v.w * v.w;
    }
    __shared__ float r1[256], r2[256];
    int t = threadIdx.x;
    r1[t] = s; r2[t] = ss; __syncthreads();
    for (int o = 128; o > 0; o >>= 1) {
        if (t < o) { r1[t] += r1[t + o]; r2[t] += r2[t + o]; }
        __syncthreads();
    }
    if (t == 0) { atomicAdd(&st[2 * b], r1[0]); atomicAdd(&st[2 * b + 1], r2[0]); }
}

// ---------- LayerNorm apply (full tensor, in-place capable) ----------
__global__ __launch_bounds__(256) void ln_apply_k(const float* __restrict__ src,
                                                  const float* __restrict__ w,
                                                  const float* __restrict__ bb,
                                                  const float* __restrict__ st,
                                                  float* __restrict__ dst) {
    size_t i4 = (size_t)blockIdx.x * 256 + threadIdx.x;
    int b = (int)(i4 / (CHW / 4));
    size_t cw4 = i4 % (CHW / 4);
    float mean = st[2 * b] * (1.0f / CHW);
    float var  = st[2 * b + 1] * (1.0f / CHW) - mean * mean;
    float rstd = rsqrtf(var + LNEPS);
    float4 v  = ((const float4*)src)[i4];
    float4 wv = ((const float4*)w)[cw4];
    float4 bv = ((const float4*)bb)[cw4];
    float4 o;
    o.x = (v.x - mean) * rstd * wv.x + bv.x;
    o.y = (v.y - mean) * rstd * wv.y + bv.y;
    o.z = (v.z - mean) * rstd * wv.z + bv.z;
    o.w = (v.w - mean) * rstd * wv.w + bv.w;
    ((float4*)dst)[i4] = o;
}

// ---------- tiled fp32 GEMM: Out[b,o,p] = sum_c W[o,c]*In'[b,c,p] + bias[o] ----------
// LN: In' = (In - mu_b)*rstd_b*lnw + lnb applied during B-tile staging.
// 128x128 tile, BK=16, 256 threads, 8x8 per thread. blockIdx.z = chunk-local batch.
template<int ACT, int ACC, int LN>
__global__ __launch_bounds__(256) void gemm_k(const float* __restrict__ In,
                                              const float* __restrict__ Wt,
                                              const float* __restrict__ bias,
                                              float* __restrict__ Out,
                                              int Cin, int Oout,
                                              const float* __restrict__ lnw,
                                              const float* __restrict__ lnb,
                                              const float* __restrict__ st) {
    const int bz = blockIdx.z;
    const int p0 = blockIdx.x * 128;
    const int o0 = blockIdx.y * 128;
    const float* in = In + (size_t)bz * Cin * HWS;
    float* out = Out + (size_t)bz * Oout * HWS;

    float mean = 0.f, rstd = 1.f;
    if (LN) {
        mean = st[2 * bz] * (1.0f / CHW);
        float var = st[2 * bz + 1] * (1.0f / CHW) - mean * mean;
        rstd = rsqrtf(var + LNEPS);
    }

    __shared__ float As[16][132];   // [k][o]
    __shared__ float Bs[16][132];   // [k][p]

    const int tid = threadIdx.x;
    const int tm = tid >> 4;        // o-group
    const int tn = tid & 15;        // p-group

    float acc[8][8];
#pragma unroll
    for (int i = 0; i < 8; ++i)
#pragma unroll
        for (int j = 0; j < 8; ++j) acc[i][j] = 0.f;

    for (int k0 = 0; k0 < Cin; k0 += 16) {
#pragma unroll
        for (int i = 0; i < 2; ++i) {       // A: 128 o x 16 k
            int fi = tid + i * 256;
            int row = fi >> 2, col = fi & 3;
            float4 v = *(const float4*)(Wt + (size_t)(o0 + row) * Cin + k0 + col * 4);
            As[col * 4 + 0][row] = v.x;
            As[col * 4 + 1][row] = v.y;
            As[col * 4 + 2][row] = v.z;
            As[col * 4 + 3][row] = v.w;
        }
#pragma unroll
        for (int i = 0; i < 2; ++i) {       // B: 16 k x 128 p
            int fi = tid + i * 256;
            int c = fi >> 5, pq = fi & 31;
            size_t off = (size_t)(k0 + c) * HWS + p0 + pq * 4;   // within-batch offset
            float4 v = *(const float4*)(in + off);
            if (LN) {
                float4 wv = *(const float4*)(lnw + off);
                float4 bv = *(const float4*)(lnb + off);
                v.x = (v.x - mean) * rstd * wv.x + bv.x;
                v.y = (v.y - mean) * rstd * wv.y + bv.y;
                v.z = (v.z - mean) * rstd * wv.z + bv.z;
                v.w = (v.w - mean) * rstd * wv.w + bv.w;
            }
            *(float4*)&Bs[c][pq * 4] = v;
        }
        __syncthreads();
#pragma unroll
        for (int k = 0; k < 16; ++k) {
            float4 a0 = *(const float4*)&As[k][tm * 8];
            float4 a1 = *(const float4*)&As[k][tm * 8 + 4];
            float4 b0 = *(const float4*)&Bs[k][tn * 8];
            float4 b1 = *(const float4*)&Bs[k][tn * 8 + 4];
            float av[8] = {a0.x, a0.y, a0.z, a0.w, a1.x, a1.y, a1.z, a1.w};
            float bv[8] = {b0.x, b0.y, b0.z, b0.w, b1.x, b1.y, b1.z, b1.w};
#pragma unroll
            for (int i = 0; i < 8; ++i)
#pragma unroll
                for (int j = 0; j < 8; ++j)
                    acc[i][j] = fmaf(av[i], bv[j], acc[i][j]);
        }
        __syncthreads();
    }

#pragma unroll
    for (int i = 0; i < 8; ++i) {
        int o = o0 + tm * 8 + i;
        float bvs = bias[o];
#pragma unroll
        for (int jj = 0; jj < 2; ++jj) {
            size_t idx = (size_t)o * HWS + p0 + tn * 8 + jj * 4;
            float4 v;
            v.x = acc[i][jj * 4 + 0] + bvs;
            v.y = acc[i][jj * 4 + 1] + bvs;
            v.z = acc[i][jj * 4 + 2] + bvs;
            v.w = acc[i][jj * 4 + 3] + bvs;
            if (ACT) { v.x = gelu_f(v.x); v.y = gelu_f(v.y); v.z = gelu_f(v.z); v.w = gelu_f(v.w); }
            if (ACC) {
                float4 prev = *(const float4*)(out + idx);
                v.x += prev.x; v.y += prev.y; v.z += prev.z; v.w += prev.w;
            }
            *(float4*)(out + idx) = v;
        }
    }
}

// ---------- softmax over channel dim (per pixel), in place; chunk-local ----------
__global__ __launch_bounds__(64) void softmax_c_k(float* __restrict__ Q) {
    int gp = blockIdx.x * 64 + threadIdx.x;
    int b = gp >> 12;          // local batch
    int p = gp & 4095;
    float* base = Q + (size_t)b * CCH * HWS + p;
    float m = -1e30f, s = 0.f;
#pragma unroll 4
    for (int c = 0; c < CCH; ++c) {
        float v = base[(size_t)c * HWS];
        float mn = fmaxf(m, v);
        s = s * __expf(m - mn) + __expf(v - mn);
        m = mn;
    }
    float inv = 1.0f / s;
#pragma unroll 4
    for (int c = 0; c < CCH; ++c) {
        size_t idx = (size_t)c * HWS;
        base[idx] = __expf(base[idx] - m) * inv;
    }
}

// ---------- softmax over spatial dim (per b,channel), in place; chunk-local ----------
__global__ __launch_bounds__(256) void softmax_s_k(float* __restrict__ K) {
    size_t row = blockIdx.x;
    float* base = K + row * HWS;
    int t = threadIdx.x;
    float4 v[4];
    float lm = -1e30f;
#pragma unroll
    for (int i = 0; i < 4; ++i) {
        v[i] = ((const float4*)base)[t + i * 256];
        lm = fmaxf(lm, fmaxf(fmaxf(v[i].x, v[i].y), fmaxf(v[i].z, v[i].w)));
    }
    __shared__ float red[256];
    red[t] = lm; __syncthreads();
    for (int o = 128; o > 0; o >>= 1) { if (t < o) red[t] = fmaxf(red[t], red[t + o]); __syncthreads(); }
    float m = red[0];
    __syncthreads();
    float ls = 0.f;
#pragma unroll
    for (int i = 0; i < 4; ++i) {
        v[i].x = __expf(v[i].x - m); v[i].y = __expf(v[i].y - m);
        v[i].z = __expf(v[i].z - m); v[i].w = __expf(v[i].w - m);
        ls += v[i].x + v[i].y + v[i].z + v[i].w;
    }
    red[t] = ls; __syncthreads();
    for (int o = 128; o > 0; o >>= 1) { if (t < o) red[t] += red[t + o]; __syncthreads(); }
    float inv = 1.0f / red[0];
#pragma unroll
    for (int i = 0; i < 4; ++i) {
        v[i].x *= inv; v[i].y *= inv; v[i].z *= inv; v[i].w *= inv;
        ((float4*)base)[t + i * 256] = v[i];
    }
}

// ---------- KV[b,h,k,v] = sum_p K[b,hk,p]*V[b,hv,p]; chunk-local b ----------
__global__ __launch_bounds__(256) void kv_k(const float* __restrict__ K,
                                            const float* __restrict__ V,
                                            float* __restrict__ KV) {
    int b = blockIdx.z, h = blockIdx.y, pc = blockIdx.x;   // pc: 0..7, 512 pixels each
    const float* kb = K + ((size_t)b * CCH + h * HD) * HWS + pc * 512;
    const float* vb = V + ((size_t)b * CCH + h * HD) * HWS + pc * 512;
    float* kvb = KV + (size_t)(b * NHEAD + h) * (HD * HD);

    __shared__ float Ks[64][68];   // [p][c]
    __shared__ float Vs[64][68];

    int tid = threadIdx.x;
    int tk = tid >> 4, tv = tid & 15;
    float acc[4][4];
#pragma unroll
    for (int i = 0; i < 4; ++i)
#pragma unroll
        for (int j = 0; j < 4; ++j) acc[i][j] = 0.f;

    for (int sc = 0; sc < 8; ++sc) {
#pragma unroll
        for (int r = 0; r < 4; ++r) {
            int li = tid + r * 256;              // float4 index over 64c x 16
            int c = li >> 4, pq = li & 15;
            float4 kv4 = *(const float4*)(kb + (size_t)c * HWS + sc * 64 + pq * 4);
            float4 vv4 = *(const float4*)(vb + (size_t)c * HWS + sc * 64 + pq * 4);
            Ks[pq * 4 + 0][c] = kv4.x; Ks[pq * 4 + 1][c] = kv4.y;
            Ks[pq * 4 + 2][c] = kv4.z; Ks[pq * 4 + 3][c] = kv4.w;
            Vs[pq * 4 + 0][c] = vv4.x; Vs[pq * 4 + 1][c] = vv4.y;
            Vs[pq * 4 + 2][c] = vv4.z; Vs[pq * 4 + 3][c] = vv4.w;
        }
        __syncthreads();
#pragma unroll 8
        for (int p = 0; p < 64; ++p) {
            float4 ka = *(const float4*)&Ks[p][tk * 4];
            float4 va = *(const float4*)&Vs[p][tv * 4];
            float kav[4] = {ka.x, ka.y, ka.z, ka.w};
            float vav[4] = {va.x, va.y, va.z, va.w};
#pragma unroll
            for (int i = 0; i < 4; ++i)
#pragma unroll
                for (int j = 0; j < 4; ++j)
                    acc[i][j] = fmaf(kav[i], vav[j], acc[i][j]);
        }
        __syncthreads();
    }
#pragma unroll
    for (int i = 0; i < 4; ++i)
#pragma unroll
        for (int j = 0; j < 4; ++j)
            atomicAdd(&kvb[(size_t)(tk * 4 + i) * HD + tv * 4 + j], acc[i][j]);
}

// ---------- attn[b,hv,p] = sum_k KV[b,h,k,v]*Q[b,hk,p]; chunk-local b ----------
__global__ __launch_bounds__(256) void attn_k(const float* __restrict__ Q,
                                              const float* __restrict__ KV,
                                              float* __restrict__ Out) {
    int b = blockIdx.z, h = blockIdx.y, pt = blockIdx.x;  // pt: 0..63
    const float* qb = Q + ((size_t)b * CCH + h * HD) * HWS + pt * 64;
    const float* kvb = KV + (size_t)(b * NHEAD + h) * (HD * HD);
    float* ob = Out + ((size_t)b * CCH + h * HD) * HWS + pt * 64;

    __shared__ float KVs[64][68];  // [k][v]
    __shared__ float Qs[16][68];   // [k][p]

    int tid = threadIdx.x;
    int ti = tid >> 4;   // v-group
    int tp = tid & 15;   // p-group

#pragma unroll
    for (int r = 0; r < 4; ++r) {
        int li = tid + r * 256;
        int k = li >> 4, vq = li & 15;
        float4 v = *(const float4*)(kvb + (size_t)k * HD + vq * 4);
        *(float4*)&KVs[k][vq * 4] = v;
    }
    float acc[4][4];
#pragma unroll
    for (int i = 0; i < 4; ++i)
#pragma unroll
        for (int j = 0; j < 4; ++j) acc[i][j] = 0.f;

    for (int kc = 0; kc < 64; kc += 16) {
        {
            int c = tid >> 4, pq = tid & 15;
            float4 v = *(const float4*)(qb + (size_t)(kc + c) * HWS + pq * 4);
            *(float4*)&Qs[c][pq * 4] = v;
        }
        __syncthreads();
#pragma unroll
        for (int k = 0; k < 16; ++k) {
            float4 kv4 = *(const float4*)&KVs[kc + k][ti * 4];
            float4 q4  = *(const float4*)&Qs[k][tp * 4];
            float kva[4] = {kv4.x, kv4.y, kv4.z, kv4.w};
            float qa[4]  = {q4.x, q4.y, q4.z, q4.w};
#pragma unroll
            for (int i = 0; i < 4; ++i)
#pragma unroll
                for (int j = 0; j < 4; ++j)
                    acc[i][j] = fmaf(kva[i], qa[j], acc[i][j]);
        }
        __syncthreads();
    }
#pragma unroll
    for (int i = 0; i < 4; ++i) {
        float4 v; v.x = acc[i][0]; v.y = acc[i][1]; v.z = acc[i][2]; v.w = acc[i][3];
        *(float4*)(ob + (size_t)(ti * 4 + i) * HWS + tp * 4) = v;
    }
}

extern "C" void kernel_launch(void* const* d_in, const int* in_sizes, int n_in,
                              void* d_out, int out_size, void* d_ws, size_t ws_size,
                              hipStream_t stream) {
    const float* x    = (const float*)d_in[0];
    const float* ln1w = (const float*)d_in[1];
    const float* ln1b = (const float*)d_in[2];
    const float* qw   = (const float*)d_in[3];
    const float* qb   = (const float*)d_in[4];
    const float* kw   = (const float*)d_in[5];
    const float* kb   = (const float*)d_in[6];
    const float* vw   = (const float*)d_in[7];
    const float* vb   = (const float*)d_in[8];
    const float* huw  = (const float*)d_in[9];
    const float* hub  = (const float*)d_in[10];
    const float* ln2w = (const float*)d_in[11];
    const float* ln2b = (const float*)d_in[12];
    const float* f1w  = (const float*)d_in[13];
    const float* f1b  = (const float*)d_in[14];
    const float* f2w  = (const float*)d_in[15];
    const float* f2b  = (const float*)d_in[16];
    float* out = (float*)d_out;
    float* ws = (float*)d_ws;

    const size_t CHWb = (size_t)CCH * HWS;          // 2,097,152 floats / batch
    const size_t SZ   = (size_t)BATCH * CHWb;       // full tensor

    // Workspace layout (floats): [stats:64(+pad to 1024)] [KV: 524288] [chunk region: G*8388608]
    // chunk region holds Q|K|V (3*G*CHWb <= G*8388608) in phase 1, H (G*DHFF*HWS) in phase 2.
    // Pick largest chunk G that fits ws_size.
    int G = 16;
    while (G > 1 && ((size_t)8388608 * G + 525312) * sizeof(float) > ws_size) G >>= 1;
    const int nch = BATCH / G;

    float* stats = ws;                       // [0..31] ln1, [32..63] ln2
    float* bufKV = ws + 1024;                // BATCH*NHEAD*HD*HD = 524288 floats
    float* chunk = ws + 525312;
    float* bufQ  = chunk;
    float* bufK  = bufQ + (size_t)G * CHWb;
    float* bufV  = bufK + (size_t)G * CHWb;
    float* bufH  = chunk;                    // FFN hidden, overlays Q|K|V

    hipMemsetAsync(stats, 0, 64 * sizeof(float), stream);
    hipMemsetAsync(bufKV, 0, (size_t)BATCH * NHEAD * HD * HD * sizeof(float), stream);

    dim3 gStatsAll(64, BATCH);
    stats_k<<<gStatsAll, 256, 0, stream>>>(x, stats);

    for (int g = 0; g < nch; ++g) {
        const int cb = g * G;
        const float* xg = x + (size_t)cb * CHWb;
        float* kvg = bufKV + (size_t)cb * NHEAD * HD * HD;

        dim3 gGemm(HWS / 128, CCH / 128, G);
        // QKV with fused LN1 on the B (activation) tile
        gemm_k<0,0,1><<<gGemm, 256, 0, stream>>>(xg, qw, qb, bufQ, CCH, CCH, ln1w, ln1b, stats + 2 * cb);
        gemm_k<0,0,1><<<gGemm, 256, 0, stream>>>(xg, kw, kb, bufK, CCH, CCH, ln1w, ln1b, stats + 2 * cb);
        gemm_k<0,0,1><<<gGemm, 256, 0, stream>>>(xg, vw, vb, bufV, CCH, CCH, ln1w, ln1b, stats + 2 * cb);

        softmax_c_k<<<(G * HWS) / 64, 64, 0, stream>>>(bufQ);
        softmax_s_k<<<G * CCH, 256, 0, stream>>>(bufK);

        dim3 gKV(8, NHEAD, G);
        kv_k<<<gKV, 256, 0, stream>>>(bufK, bufV, kvg);

        dim3 gAttn(HWS / 64, NHEAD, G);
        attn_k<<<gAttn, 256, 0, stream>>>(bufQ, kvg, bufK);            // attnRaw -> bufK

        gemm_k<0,0,0><<<gGemm, 256, 0, stream>>>(bufK, huw, hub, bufV, CCH, CCH,
                                                 nullptr, nullptr, nullptr);  // attnOut -> bufV

        dim3 gStats(64, G);
        resid_stats_k<<<gStats, 256, 0, stream>>>(xg, bufV, out + (size_t)cb * CHWb,
                                                  stats + 32 + 2 * cb);       // r -> d_out
    }

    // LN2 in place on d_out (r -> x2)
    ln_apply_k<<<SZ / 4 / 256, 256, 0, stream>>>(out, ln2w, ln2b, stats + 32, out);

    for (int g = 0; g < nch; ++g) {
        const int cb = g * G;
        float* og = out + (size_t)cb * CHWb;
        dim3 gF1(HWS / 128, DHFF / 128, G);
        gemm_k<1,0,0><<<gF1, 256, 0, stream>>>(og, f1w, f1b, bufH, CCH, DHFF,
                                               nullptr, nullptr, nullptr);    // gelu(ff1)
        dim3 gF2(HWS / 128, CCH / 128, G);
        gemm_k<0,1,0><<<gF2, 256, 0, stream>>>(bufH, f2w, f2b, og, DHFF, CCH,
                                               nullptr, nullptr, nullptr);    // og = x2 + ff2
    }
}

// Round 3
// 2639.412 us; speedup vs baseline: 2.1622x; 2.1622x over previous
//
#include <hip/hip_runtime.h>
#include <math.h>

#define BATCH 16
#define CCH   512
#define HWS   4096                 // H*W
#define CHW   (CCH*HWS)            // per-batch elements: 2,097,152
#define DHFF  2048
#define NHEAD 8
#define HD    64
#define QKVLD 1536
#define LNEPS 1e-5f

typedef unsigned short u16;
typedef __bf16 bf16x8 __attribute__((ext_vector_type(8)));
typedef float f32x4 __attribute__((ext_vector_type(4)));

__device__ __forceinline__ float gelu_f(float x) {
    return 0.5f * x * (1.0f + erff(x * 0.70710678118654752440f));
}
__device__ __forceinline__ u16 f2bf(float f) {
    union { float f; unsigned u; } c; c.f = f;
    unsigned r = c.u + 0x7FFFu + ((c.u >> 16) & 1u);
    return (u16)(r >> 16);
}
__device__ __forceinline__ float bf2f(u16 h) {
    union { unsigned u; float f; } c; c.u = ((unsigned)h) << 16; return c.f;
}

// ---------- per-batch sum/sumsq over x (LN1 stats) ----------
__global__ __launch_bounds__(256) void stats_k(const float* __restrict__ src,
                                               float* __restrict__ st) {
    int b = blockIdx.y;
    const float4* p = (const float4*)(src + (size_t)b * CHW + (size_t)blockIdx.x * (CHW / 64));
    float s = 0.f, ss = 0.f;
    for (int i = threadIdx.x; i < (CHW / 64 / 4); i += 256) {
        float4 v = p[i];
        s  += v.x + v.y + v.z + v.w;
        ss += v.x * v.x + v.y * v.y + v.z * v.z + v.w * v.w;
    }
    __shared__ float r1[256], r2[256];
    int t = threadIdx.x;
    r1[t] = s; r2[t] = ss; __syncthreads();
    for (int o = 128; o > 0; o >>= 1) {
        if (t < o) { r1[t] += r1[t + o]; r2[t] += r2[t + o]; }
        __syncthreads();
    }
    if (t == 0) { atomicAdd(&st[2 * b], r1[0]); atomicAdd(&st[2 * b + 1], r2[0]); }
}

// ---------- fp32 -> bf16 flat convert (weights) ----------
__global__ __launch_bounds__(256) void cvt_k(const float* __restrict__ src,
                                             u16* __restrict__ dst, int n4) {
    int i = blockIdx.x * 256 + threadIdx.x;
    if (i >= n4) return;
    float4 v = ((const float4*)src)[i];
    uint2 o; u16* op = (u16*)&o;
    op[0] = f2bf(v.x); op[1] = f2bf(v.y); op[2] = f2bf(v.z); op[3] = f2bf(v.w);
    ((uint2*)dst)[i] = o;
}

// ---------- fp32 [c][p] -> fp32 [p][c] transpose (ln2 w/b) ----------
__global__ __launch_bounds__(256) void tr_k(const float* __restrict__ src,
                                            float* __restrict__ dst) {
    int p0 = blockIdx.x * 32, c0 = blockIdx.y * 32;
    __shared__ float T[32][33];
    int tx = threadIdx.x & 31, ty = threadIdx.x >> 5;
#pragma unroll
    for (int i = 0; i < 4; ++i)
        T[ty + i * 8][tx] = src[(size_t)(c0 + ty + i * 8) * HWS + p0 + tx];
    __syncthreads();
#pragma unroll
    for (int i = 0; i < 4; ++i)
        dst[(size_t)(p0 + ty + i * 8) * CCH + c0 + tx] = T[tx][ty + i * 8];
}

// ---------- LN1 + transpose + cvt: a[p][c] bf16 = LN1(x)[c][p] ----------
__global__ __launch_bounds__(256) void ln1t_k(const float* __restrict__ x,
                                              const float* __restrict__ w,
                                              const float* __restrict__ bb,
                                              const float* __restrict__ st,
                                              u16* __restrict__ a, int cb) {
    int p0 = blockIdx.x * 32, c0 = blockIdx.y * 32, bl = blockIdx.z;
    int b = cb + bl;
    float mean = st[2 * b] * (1.0f / CHW);
    float var  = st[2 * b + 1] * (1.0f / CHW) - mean * mean;
    float rstd = rsqrtf(var + LNEPS);
    __shared__ float T[32][33];
    int tx = threadIdx.x & 31, ty = threadIdx.x >> 5;
    const float* xb = x + (size_t)b * CHW;
#pragma unroll
    for (int i = 0; i < 4; ++i) {
        size_t o = (size_t)(c0 + ty + i * 8) * HWS + p0 + tx;
        T[ty + i * 8][tx] = (xb[o] - mean) * rstd * w[o] + bb[o];
    }
    __syncthreads();
    u16* ab = a + (size_t)bl * CHW;
#pragma unroll
    for (int i = 0; i < 4; ++i)
        ab[(size_t)(p0 + ty + i * 8) * CCH + c0 + tx] = f2bf(T[tx][ty + i * 8]);
}

// ---------- bf16 MFMA GEMM (TN): Out[m][n] = sum_k A[m][k]*B[n][k] + bias[n] ----------
// 128x128 tile, BK=32, 256 thr = 4 waves, each wave 4x4 of 16x16x32 MFMA.
template<int ACT, int OBF>
__global__ __launch_bounds__(256) void gemm_tn(const u16* __restrict__ A,
                                               const u16* __restrict__ B,
                                               const float* __restrict__ bias,
                                               void* __restrict__ Out,
                                               int K, int ldo) {
    __shared__ u16 As[128 * 40];   // [row][32k + 8 pad]
    __shared__ u16 Bs[128 * 40];
    const int tid = threadIdx.x;
    const int m0 = blockIdx.x * 128;
    const int n0 = blockIdx.y * 128;
    const int lane = tid & 63;
    const int w = tid >> 6;
    const int wm = (w & 1) * 64, wn = (w >> 1) * 64;
    const int ls = lane & 15, lq = lane >> 4;

    f32x4 acc[4][4];
#pragma unroll
    for (int i = 0; i < 4; ++i)
#pragma unroll
        for (int j = 0; j < 4; ++j) acc[i][j] = (f32x4){0.f, 0.f, 0.f, 0.f};

    // staging: 512 ushort8-chunks per tile; thread handles chunks tid and tid+256
    const int r0 = tid >> 2, q0 = tid & 3;
    const int r1 = (tid + 256) >> 2, q1 = (tid + 256) & 3;
    const u16* pa0 = A + (size_t)(m0 + r0) * K + q0 * 8;
    const u16* pa1 = A + (size_t)(m0 + r1) * K + q1 * 8;
    const u16* pb0 = B + (size_t)(n0 + r0) * K + q0 * 8;
    const u16* pb1 = B + (size_t)(n0 + r1) * K + q1 * 8;

    uint4 va0 = *(const uint4*)pa0;
    uint4 va1 = *(const uint4*)pa1;
    uint4 vb0 = *(const uint4*)pb0;
    uint4 vb1 = *(const uint4*)pb1;

    for (int kt = 0; kt < K; kt += 32) {
        __syncthreads();
        *(uint4*)&As[r0 * 40 + q0 * 8] = va0;
        *(uint4*)&As[r1 * 40 + q1 * 8] = va1;
        *(uint4*)&Bs[r0 * 40 + q0 * 8] = vb0;
        *(uint4*)&Bs[r1 * 40 + q1 * 8] = vb1;
        __syncthreads();
        if (kt + 32 < K) {
            va0 = *(const uint4*)(pa0 + kt + 32);
            va1 = *(const uint4*)(pa1 + kt + 32);
            vb0 = *(const uint4*)(pb0 + kt + 32);
            vb1 = *(const uint4*)(pb1 + kt + 32);
        }
        bf16x8 af[4], bfv[4];
#pragma unroll
        for (int i = 0; i < 4; ++i)
            af[i] = *(bf16x8*)&As[(wm + i * 16 + ls) * 40 + lq * 8];
#pragma unroll
        for (int j = 0; j < 4; ++j)
            bfv[j] = *(bf16x8*)&Bs[(wn + j * 16 + ls) * 40 + lq * 8];
#pragma unroll
        for (int i = 0; i < 4; ++i)
#pragma unroll
            for (int j = 0; j < 4; ++j)
                acc[i][j] = __builtin_amdgcn_mfma_f32_16x16x32_bf16(af[i], bfv[j], acc[i][j], 0, 0, 0);
    }

    // epilogue: D row = lq*4 + reg, col = ls
#pragma unroll
    for (int j = 0; j < 4; ++j) {
        int n = n0 + wn + j * 16 + ls;
        float bv = bias[n];
#pragma unroll
        for (int i = 0; i < 4; ++i) {
            int mb = m0 + wm + i * 16 + lq * 4;
#pragma unroll
            for (int r = 0; r < 4; ++r) {
                float v = acc[i][j][r] + bv;
                if (ACT) v = gelu_f(v);
                size_t idx = (size_t)(mb + r) * ldo + n;
                if (OBF) ((u16*)Out)[idx] = f2bf(v);
                else     ((float*)Out)[idx] = v;
            }
        }
    }
}

// ---------- softmax over Q channels (cols 0..511 of QKV rows), per pixel ----------
__global__ __launch_bounds__(256) void softmax_row_k(u16* __restrict__ QKV) {
    int m = blockIdx.x * 4 + (threadIdx.x >> 6);
    int lane = threadIdx.x & 63;
    u16* row = QKV + (size_t)m * QKVLD + lane * 8;
    uint4 raw = *(uint4*)row;
    u16* pr = (u16*)&raw;
    float v[8];
#pragma unroll
    for (int i = 0; i < 8; ++i) v[i] = bf2f(pr[i]);
    float mx = v[0];
#pragma unroll
    for (int i = 1; i < 8; ++i) mx = fmaxf(mx, v[i]);
    for (int o = 32; o > 0; o >>= 1) mx = fmaxf(mx, __shfl_xor(mx, o, 64));
    float s = 0.f;
#pragma unroll
    for (int i = 0; i < 8; ++i) { v[i] = __expf(v[i] - mx); s += v[i]; }
    for (int o = 32; o > 0; o >>= 1) s += __shfl_xor(s, o, 64);
    float inv = 1.0f / s;
#pragma unroll
    for (int i = 0; i < 8; ++i) pr[i] = f2bf(v[i] * inv);
    *(uint4*)row = raw;
}

// ---------- softmax over spatial p (cols 512..1023 of QKV), per (b, dq) ----------
__global__ __launch_bounds__(256) void softmax_col_k(u16* __restrict__ QKV) {
    int bl = blockIdx.y;
    int c = threadIdx.x & 63;
    int col = CCH + blockIdx.x * 64 + c;
    int seg = threadIdx.x >> 6;          // 0..3, each covers 1024 p
    u16* base = QKV + (size_t)bl * HWS * QKVLD + col;
    __shared__ float redm[4][64], reds[4][64];
    float mx = -1e30f;
    for (int p = seg * 1024; p < seg * 1024 + 1024; ++p)
        mx = fmaxf(mx, bf2f(base[(size_t)p * QKVLD]));
    redm[seg][c] = mx; __syncthreads();
    float m = fmaxf(fmaxf(redm[0][c], redm[1][c]), fmaxf(redm[2][c], redm[3][c]));
    float s = 0.f;
    for (int p = seg * 1024; p < seg * 1024 + 1024; ++p)
        s += __expf(bf2f(base[(size_t)p * QKVLD]) - m);
    reds[seg][c] = s; __syncthreads();
    float inv = 1.0f / (reds[0][c] + reds[1][c] + reds[2][c] + reds[3][c]);
    for (int p = seg * 1024; p < seg * 1024 + 1024; ++p) {
        size_t idx = (size_t)p * QKVLD;
        base[idx] = f2bf(__expf(bf2f(base[idx]) - m) * inv);
    }
}

// ---------- KV[b,h,k,v] = sum_p K[p][hk]*V[p][hv] (atomic over 16 p-chunks) ----------
__global__ __launch_bounds__(256) void kv_k2(const u16* __restrict__ QKV,
                                             float* __restrict__ KV) {
    int pc = blockIdx.x, h = blockIdx.y, bl = blockIdx.z;
    const u16* kbase = QKV + (size_t)bl * HWS * QKVLD + CCH + h * HD;
    const u16* vbase = kbase + CCH;
    float* kvb = KV + ((size_t)bl * NHEAD + h) * (HD * HD);
    __shared__ float Ks[64][65], Vs[64][65];
    int tid = threadIdx.x;
    int tk = tid >> 4, tv = tid & 15;
    float acc[4][4];
#pragma unroll
    for (int i = 0; i < 4; ++i)
#pragma unroll
        for (int j = 0; j < 4; ++j) acc[i][j] = 0.f;

    for (int s = 0; s < 4; ++s) {
        int pbase = pc * 256 + s * 64;
        __syncthreads();
#pragma unroll
        for (int j = 0; j < 2; ++j) {
            int li = tid + j * 256;
            int pl = li >> 3, c8 = (li & 7) * 8;
            uint4 kr = *(const uint4*)(kbase + (size_t)(pbase + pl) * QKVLD + c8);
            uint4 vr = *(const uint4*)(vbase + (size_t)(pbase + pl) * QKVLD + c8);
            u16* kp = (u16*)&kr; u16* vp = (u16*)&vr;
#pragma unroll
            for (int t = 0; t < 8; ++t) { Ks[pl][c8 + t] = bf2f(kp[t]); Vs[pl][c8 + t] = bf2f(vp[t]); }
        }
        __syncthreads();
#pragma unroll 4
        for (int p = 0; p < 64; ++p) {
            float ka[4], va[4];
#pragma unroll
            for (int i = 0; i < 4; ++i) { ka[i] = Ks[p][tk * 4 + i]; va[i] = Vs[p][tv * 4 + i]; }
#pragma unroll
            for (int i = 0; i < 4; ++i)
#pragma unroll
                for (int j = 0; j < 4; ++j) acc[i][j] += ka[i] * va[j];
        }
    }
#pragma unroll
    for (int i = 0; i < 4; ++i)
#pragma unroll
        for (int j = 0; j < 4; ++j)
            atomicAdd(&kvb[(size_t)(tk * 4 + i) * HD + tv * 4 + j], acc[i][j]);
}

// ---------- attnRaw[p][hv] bf16 = sum_k KV[k][v]*Q[p][hk] ----------
__global__ __launch_bounds__(256) void attn_k2(const u16* __restrict__ QKV,
                                               const float* __restrict__ KV,
                                               u16* __restrict__ attnRaw) {
    int pt = blockIdx.x, h = blockIdx.y, bl = blockIdx.z;
    const u16* qbase = QKV + (size_t)bl * HWS * QKVLD + h * HD;
    const float* kvb = KV + ((size_t)bl * NHEAD + h) * (HD * HD);
    __shared__ float KVs[64][68], Qs[64][68];
    int tid = threadIdx.x;
#pragma unroll
    for (int j = 0; j < 4; ++j) {
        int li = tid + j * 256;
        int k = li >> 4, c4 = (li & 15) * 4;
        *(float4*)&KVs[k][c4] = *(const float4*)(kvb + (size_t)k * HD + c4);
    }
#pragma unroll
    for (int j = 0; j < 2; ++j) {
        int li = tid + j * 256;
        int pl = li >> 3, c8 = (li & 7) * 8;
        uint4 qr = *(const uint4*)(qbase + (size_t)(pt * 64 + pl) * QKVLD + c8);
        u16* qp = (u16*)&qr;
#pragma unroll
        for (int t = 0; t < 8; ++t) Qs[pl][c8 + t] = bf2f(qp[t]);
    }
    __syncthreads();
    int tp = tid >> 4, tv = tid & 15;
    float acc[4][4];
#pragma unroll
    for (int i = 0; i < 4; ++i)
#pragma unroll
        for (int j = 0; j < 4; ++j) acc[i][j] = 0.f;
#pragma unroll 4
    for (int k = 0; k < 64; ++k) {
        float qa[4], kv4[4];
#pragma unroll
        for (int i = 0; i < 4; ++i) { qa[i] = Qs[tp * 4 + i][k]; kv4[i] = KVs[k][tv * 4 + i]; }
#pragma unroll
        for (int i = 0; i < 4; ++i)
#pragma unroll
            for (int j = 0; j < 4; ++j) acc[i][j] += qa[i] * kv4[j];
    }
#pragma unroll
    for (int i = 0; i < 4; ++i) {
        uint2 wv; u16* wp = (u16*)&wv;
#pragma unroll
        for (int j = 0; j < 4; ++j) wp[j] = f2bf(acc[i][j]);
        *(uint2*)(attnRaw + (size_t)(bl * HWS + pt * 64 + tp * 4 + i) * CCH + h * HD + tv * 4) = wv;
    }
}

// ---------- r[p][c] = x[c][p] + attnOut[p][c], + LN2 stats ----------
__global__ __launch_bounds__(256) void resid_t_k(const float* __restrict__ x,
                                                 const float* __restrict__ ao,
                                                 float* __restrict__ r,
                                                 float* __restrict__ st, int cb) {
    int p0 = blockIdx.x * 32, c0 = blockIdx.y * 32, bl = blockIdx.z;
    int b = cb + bl;
    __shared__ float T[32][33];
    __shared__ float r1[256], r2[256];
    int tx = threadIdx.x & 31, ty = threadIdx.x >> 5;
    const float* xb = x + (size_t)b * CHW;
#pragma unroll
    for (int i = 0; i < 4; ++i)
        T[ty + i * 8][tx] = xb[(size_t)(c0 + ty + i * 8) * HWS + p0 + tx];
    __syncthreads();
    float s = 0.f, ss = 0.f;
#pragma unroll
    for (int i = 0; i < 4; ++i) {
        size_t o = (size_t)bl * CHW + (size_t)(p0 + ty + i * 8) * CCH + c0 + tx;
        float v = T[tx][ty + i * 8] + ao[o];
        r[o] = v; s += v; ss += v * v;
    }
    int t = threadIdx.x;
    r1[t] = s; r2[t] = ss; __syncthreads();
    for (int o = 128; o > 0; o >>= 1) {
        if (t < o) { r1[t] += r1[t + o]; r2[t] += r2[t + o]; }
        __syncthreads();
    }
    if (t == 0) { atomicAdd(&st[32 + 2 * b], r1[0]); atomicAdd(&st[32 + 2 * b + 1], r2[0]); }
}

// ---------- x2 bf16 [p][c] = LN2(r) ----------
__global__ __launch_bounds__(256) void ln2a_k(const float* __restrict__ r,
                                              const float* __restrict__ w2t,
                                              const float* __restrict__ b2t,
                                              const float* __restrict__ st,
                                              u16* __restrict__ x2, int cb) {
    size_t i4 = (size_t)blockIdx.x * 256 + threadIdx.x;
    int bl = (int)(i4 / (CHW / 4));
    int b = cb + bl;
    size_t off4 = i4 % (CHW / 4);
    float mean = st[32 + 2 * b] * (1.0f / CHW);
    float var  = st[32 + 2 * b + 1] * (1.0f / CHW) - mean * mean;
    float rstd = rsqrtf(var + LNEPS);
    float4 v  = ((const float4*)(r + (size_t)bl * CHW))[off4];
    float4 wv = ((const float4*)w2t)[off4];
    float4 bv = ((const float4*)b2t)[off4];
    uint2 o; u16* op = (u16*)&o;
    op[0] = f2bf((v.x - mean) * rstd * wv.x + bv.x);
    op[1] = f2bf((v.y - mean) * rstd * wv.y + bv.y);
    op[2] = f2bf((v.z - mean) * rstd * wv.z + bv.z);
    op[3] = f2bf((v.w - mean) * rstd * wv.w + bv.w);
    ((uint2*)(x2 + (size_t)bl * CHW))[off4] = o;
}

// ---------- out[c][p] = x2[p][c] + ffOut[p][c] (transpose back) ----------
__global__ __launch_bounds__(256) void final_t_k(const u16* __restrict__ x2,
                                                 const float* __restrict__ ffo,
                                                 float* __restrict__ out, int cb) {
    int c0 = blockIdx.x * 32, p0 = blockIdx.y * 32, bl = blockIdx.z;
    int b = cb + bl;
    __shared__ float T[32][33];
    int tx = threadIdx.x & 31, ty = threadIdx.x >> 5;
#pragma unroll
    for (int i = 0; i < 4; ++i) {
        size_t o = (size_t)bl * CHW + (size_t)(p0 + ty + i * 8) * CCH + c0 + tx;
        T[ty + i * 8][tx] = ffo[o] + bf2f(x2[o]);   // T[p_local][c_local]
    }
    __syncthreads();
    float* ob = out + (size_t)b * CHW;
#pragma unroll
    for (int i = 0; i < 4; ++i)
        ob[(size_t)(c0 + ty + i * 8) * HWS + p0 + tx] = T[tx][ty + i * 8];
}

extern "C" void kernel_launch(void* const* d_in, const int* in_sizes, int n_in,
                              void* d_out, int out_size, void* d_ws, size_t ws_size,
                              hipStream_t stream) {
    const float* x    = (const float*)d_in[0];
    const float* ln1w = (const float*)d_in[1];
    const float* ln1b = (const float*)d_in[2];
    const float* qw   = (const float*)d_in[3];
    const float* qb   = (const float*)d_in[4];
    const float* kw   = (const float*)d_in[5];
    const float* kb   = (const float*)d_in[6];
    const float* vw   = (const float*)d_in[7];
    const float* vb   = (const float*)d_in[8];
    const float* huw  = (const float*)d_in[9];
    const float* hub  = (const float*)d_in[10];
    const float* ln2w = (const float*)d_in[11];
    const float* ln2b = (const float*)d_in[12];
    const float* f1w  = (const float*)d_in[13];
    const float* f1b  = (const float*)d_in[14];
    const float* f2w  = (const float*)d_in[15];
    const float* f2b  = (const float*)d_in[16];
    float* out = (float*)d_out;
    float* ws = (float*)d_ws;

    // fixed ws region (floats)
    float* stats = ws;                      // 64
    float* qkvb  = ws + 64;                 // 1536
    u16*   wqkv  = (u16*)(ws + 1600);       // 1536x512 bf16 -> 393216 f
    u16*   whu   = (u16*)(ws + 394816);     // 512x512        -> 131072 f
    u16*   wf1   = (u16*)(ws + 525888);     // 2048x512       -> 524288 f
    u16*   wf2   = (u16*)(ws + 1050176);    // 512x2048       -> 524288 f
    float* w2t   = ws + 1574464;            // 2097152 f
    float* b2t   = ws + 3671616;            // 2097152 f
    float* kvbuf = ws + 5768768;            // G*32768 f

    // chunk size G: fixed(5768768) + G*32768 + region 3.5*G*2097152
    int G = 16;
    while (G > 1 && (5768768ull + (size_t)G * 7372800ull) * 4ull > ws_size) G >>= 1;
    const int nch = BATCH / G;
    const size_t U = (size_t)G * CHW;       // chunk elems (== floats for fp32 bufs)

    float* R       = kvbuf + (size_t)G * 32768;
    u16*   a_bf    = (u16*)R;               // CHWg bf16 (also attnRaw)
    u16*   QKVb    = (u16*)(R + U / 2);     // 3*CHWg bf16
    float* attnOut = R + U / 2;             // CHWg f32 (overlays QKV after attn)
    float* rbuf    = R + 3 * U / 2;         // CHWg f32
    u16*   x2bf    = (u16*)R;               // CHWg bf16 (overlays attnRaw)
    u16*   Hbuf    = (u16*)(R + U / 2);     // 4*CHWg bf16 (overlays attnOut,r)
    float* ffOut   = R + 5 * U / 2;         // CHWg f32

    hipMemsetAsync(stats, 0, 64 * sizeof(float), stream);

    // weight conversions (every call; inputs restored by harness each iter)
    cvt_k<<<dim3(256), 256, 0, stream>>>(qw, wqkv, 65536);
    cvt_k<<<dim3(256), 256, 0, stream>>>(kw, wqkv + 262144, 65536);
    cvt_k<<<dim3(256), 256, 0, stream>>>(vw, wqkv + 524288, 65536);
    cvt_k<<<dim3(256), 256, 0, stream>>>(huw, whu, 65536);
    cvt_k<<<dim3(1024), 256, 0, stream>>>(f1w, wf1, 262144);
    cvt_k<<<dim3(1024), 256, 0, stream>>>(f2w, wf2, 262144);
    tr_k<<<dim3(128, 16), 256, 0, stream>>>(ln2w, w2t);
    tr_k<<<dim3(128, 16), 256, 0, stream>>>(ln2b, b2t);
    hipMemcpyAsync(qkvb,        qb, 512 * sizeof(float), hipMemcpyDeviceToDevice, stream);
    hipMemcpyAsync(qkvb + 512,  kb, 512 * sizeof(float), hipMemcpyDeviceToDevice, stream);
    hipMemcpyAsync(qkvb + 1024, vb, 512 * sizeof(float), hipMemcpyDeviceToDevice, stream);

    stats_k<<<dim3(64, BATCH), 256, 0, stream>>>(x, stats);

    for (int g = 0; g < nch; ++g) {
        const int cb = g * G;
        // LN1 + transpose + cvt -> a[p][c] bf16
        ln1t_k<<<dim3(128, 16, G), 256, 0, stream>>>(x, ln1w, ln1b, stats, a_bf, cb);
        // fused QKV GEMM: [G*4096 x 512] x [1536 x 512]^T -> bf16 [m][1536]
        gemm_tn<0, 1><<<dim3(G * 32, 12), 256, 0, stream>>>(a_bf, wqkv, qkvb, QKVb, CCH, QKVLD);
        softmax_row_k<<<dim3(G * 1024), 256, 0, stream>>>(QKVb);
        softmax_col_k<<<dim3(8, G), 256, 0, stream>>>(QKVb);
        hipMemsetAsync(kvbuf, 0, (size_t)G * 32768 * sizeof(float), stream);
        kv_k2<<<dim3(16, NHEAD, G), 256, 0, stream>>>(QKVb, kvbuf);
        attn_k2<<<dim3(64, NHEAD, G), 256, 0, stream>>>(QKVb, kvbuf, a_bf);  // attnRaw over a
        // hu GEMM -> attnOut fp32 [m][512]
        gemm_tn<0, 0><<<dim3(G * 32, 4), 256, 0, stream>>>(a_bf, whu, hub, attnOut, CCH, CCH);
        resid_t_k<<<dim3(128, 16, G), 256, 0, stream>>>(x, attnOut, rbuf, stats, cb);
        ln2a_k<<<dim3(G * 2048), 256, 0, stream>>>(rbuf, w2t, b2t, stats, x2bf, cb);
        // ff1 GEMM + gelu -> H bf16 [m][2048]
        gemm_tn<1, 1><<<dim3(G * 32, 16), 256, 0, stream>>>(x2bf, wf1, f1b, Hbuf, CCH, DHFF);
        // ff2 GEMM -> ffOut fp32 [m][512]
        gemm_tn<0, 0><<<dim3(G * 32, 4), 256, 0, stream>>>(Hbuf, wf2, f2b, ffOut, DHFF, CCH);
        // out[c][p] = x2 + ff
        final_t_k<<<dim3(16, 128, G), 256, 0, stream>>>(x2bf, ffOut, out, cb);
    }
}